// Round 8
// baseline (81.157 us; speedup 1.0000x reference)
//
#include <hip/hip_runtime.h>
#include <hip/hip_bf16.h>

#define NN 8192
#define DD 64
#define NT 16            // j-tiles per block (tile = 64 j-cols)

typedef __attribute__((ext_vector_type(8))) short short8;
typedef __attribute__((ext_vector_type(4))) float floatx4;
typedef __attribute__((ext_vector_type(4))) int intx4;

// compile-time-indexed 4-way select (avoids runtime ext_vector indexing -> scratch)
__device__ __forceinline__ float sel4(floatx4 v, int r) {
    float a = (r & 1) ? v[1] : v[0];
    float b = (r & 1) ? v[3] : v[2];
    return (r & 2) ? b : a;
}

// ---------------- prep: per-row stats in fp32, Z -> bf16 ----------------
__global__ __launch_bounds__(256) void prep_kernel(const float* __restrict__ Z,
                                                   unsigned short* __restrict__ Zb,
                                                   float* __restrict__ u,
                                                   float* __restrict__ v) {
    int row = blockIdx.x * 4 + (threadIdx.x >> 6);
    int lane = threadIdx.x & 63;
    float z = Z[(size_t)row * DD + lane];
    __hip_bfloat16 zb = __float2bfloat16(z);
    Zb[(size_t)row * DD + lane] = *(unsigned short*)&zb;
    float sq = z * z;
    float s = z;
    for (int off = 32; off; off >>= 1) {
        sq += __shfl_xor(sq, off);
        s  += __shfl_xor(s,  off);
    }
    if (lane == 0) {
        const float deps2 = (float)DD * 1e-6f * 1e-6f;
        u[row] = sq + 2e-6f * s + deps2;  // i-side: sq_i + 2*eps*s_i + D*eps^2
        v[row] = sq - 2e-6f * s;          // j-side: sq_j - 2*eps*s_j
    }
}

// ---------------- main: PERSISTENT blocks (512 = 2/CU), registers-only A ----------------
// Block owns i-rows [bi*128,+128), loops NT=16 j-tiles of 64. Wave owns 32 i-rows.
// Per tile each lane holds its A as 8 intx4 in REGISTERS (double-buffered).
// Issue order per body (pinned by sched_barriers):
//   wait vmcnt(8)  [only ALOAD(t+1) may remain in flight]
//   MFMA (consumes bf(t))
//   issue bf(t+1) (single-buffer, regs free after MFMA) + vjaj(t+1) (double-buffer)
//   pure-VALU epilogue on A(t) regs
//   sched_barrier; issue ALOAD(t+2)  <- ALWAYS the newest ops, so the vmcnt(8)
//   window keeps exactly one A-tile in flight and never force-drains it.
// Swapped MFMA operands: lane owns (i = iBaseW+m*16+llo, j = jBase+n*16+lhi*4+r).
// Branchless softplus ~= e^theta; true diagonal gets exact bit-identical cancel.
__global__ __launch_bounds__(256, 2) void main_kernel(const unsigned short* __restrict__ Zb,
                                                      const float* __restrict__ u,
                                                      const float* __restrict__ v,
                                                      const float* __restrict__ alpha,
                                                      const int* __restrict__ A,
                                                      float* __restrict__ partials) {
    __shared__ float red[4];

    int blk = blockIdx.x;
    int bi = blk >> 3;                  // 0..63 -> i-rows bi*128..+128
    int jg = blk & 7;                   // 0..7  -> j-cols jg*1024..+1024
    int tid = threadIdx.x;
    int wid = tid >> 6;
    int lane = tid & 63;
    int iBaseW = bi * 128 + wid * 32;
    int jBase0 = jg * (NT * 64);
    int lhi = lane >> 4;                // 0..3
    int llo = lane & 15;                // 0..15
    int kb  = lhi * 8;                  // k-offset within 32-wide k-step

    // ---- i-side fragments + stats, loaded once (L2-hot)
    short8 af[2][2];
#pragma unroll
    for (int m = 0; m < 2; ++m) {
        const unsigned short* pa = &Zb[(size_t)(iBaseW + m * 16 + llo) * DD + kb];
        af[m][0] = *(const short8*)pa;
        af[m][1] = *(const short8*)(pa + 32);
    }
    float ui[2];
#pragma unroll
    for (int m = 0; m < 2; ++m) ui[m] = u[iBaseW + m * 16 + llo];

    intx4 Aa[2][4], Ab[2][4];           // double-buffered A (32 VGPR each)
    short8 bf[4][2];                    // j-fragments, single-buffered
    floatx4 vj0[4], aj0[4], vj1[4], aj1[4];

#define ALOAD(BUF, t)                                                             \
    {                                                                             \
        _Pragma("unroll") for (int m = 0; m < 2; ++m) {                           \
            const int* Ap = &A[(size_t)(iBaseW + m * 16 + llo) * NN               \
                               + jBase0 + (t) * 64 + lhi * 4];                    \
            _Pragma("unroll") for (int n = 0; n < 4; ++n)                         \
                BUF[m][n] = *(const intx4*)(Ap + n * 16);                         \
        }                                                                         \
    }
#define JLOAD(t)                                                                  \
    {                                                                             \
        _Pragma("unroll") for (int n = 0; n < 4; ++n) {                           \
            const unsigned short* pb =                                            \
                &Zb[(size_t)(jBase0 + (t) * 64 + n * 16 + llo) * DD + kb];        \
            bf[n][0] = *(const short8*)pb;                                        \
            bf[n][1] = *(const short8*)(pb + 32);                                 \
        }                                                                         \
    }
#define VLOAD(VJ, AJ, t)                                                          \
    {                                                                             \
        _Pragma("unroll") for (int n = 0; n < 4; ++n) {                           \
            VJ[n] = *(const floatx4*)&v[jBase0 + (t) * 64 + n * 16 + lhi * 4];    \
            AJ[n] = *(const floatx4*)&alpha[jBase0 + (t) * 64 + n * 16 + lhi * 4];\
        }                                                                         \
    }

    // prologue: A(0), j-side(0), then A(1) pinned as the newest 8 vmem ops
    ALOAD(Aa, 0);
    JLOAD(0);
    VLOAD(vj0, aj0, 0);
    __builtin_amdgcn_sched_barrier(0);
    ALOAD(Ab, 1);

    float ll = 0.f;

#define TBODY(t, ACUR, VJC, AJC, VJN, AJN)                                        \
    {                                                                             \
        if ((t) < NT - 1) asm volatile("s_waitcnt vmcnt(8)" ::: "memory");        \
        else              asm volatile("s_waitcnt vmcnt(0)" ::: "memory");        \
        floatx4 acc[2][4];                                                        \
        _Pragma("unroll") for (int m = 0; m < 2; ++m)                             \
            _Pragma("unroll") for (int n = 0; n < 4; ++n)                         \
                acc[m][n] = (floatx4){0.f, 0.f, 0.f, 0.f};                        \
        _Pragma("unroll") for (int kk = 0; kk < 2; ++kk)                          \
            _Pragma("unroll") for (int m = 0; m < 2; ++m)                         \
                _Pragma("unroll") for (int n = 0; n < 4; ++n)                     \
                    acc[m][n] = __builtin_amdgcn_mfma_f32_16x16x32_bf16(          \
                        bf[n][kk], af[m][kk], acc[m][n], 0, 0, 0);                \
        if ((t) + 1 < NT) { JLOAD((t) + 1); VLOAD(VJN, AJN, (t) + 1); }           \
        _Pragma("unroll") for (int m = 0; m < 2; ++m)                             \
            _Pragma("unroll") for (int n = 0; n < 4; ++n)                         \
                _Pragma("unroll") for (int r = 0; r < 4; ++r) {                   \
                    float g = acc[m][n][r];                                       \
                    float d2 = fmaf(-2.f, g, ui[m] + VJC[n][r]);                  \
                    float zd = __builtin_amdgcn_sqrtf(fmaxf(d2, 0.f));            \
                    float th = AJC[n][r] - zd;                                    \
                    float sp = __expf(th);                                        \
                    ll += (ACUR[m][n][r] ? th : 0.f) - sp;                        \
                }                                                                 \
        int dd = iBaseW - (jBase0 + (t) * 64);                                    \
        if (__builtin_expect(dd >= -16 && dd <= 48, 0)) {                         \
            if ((llo >> 2) == lhi) {                                              \
                int r = llo & 3;                                                  \
                _Pragma("unroll") for (int m = 0; m < 2; ++m)                     \
                    _Pragma("unroll") for (int n = 0; n < 4; ++n)                 \
                        if (n * 16 - m * 16 == dd) {                              \
                            float g = sel4(acc[m][n], r);                         \
                            float d2 = fmaf(-2.f, g, ui[m] + sel4(VJC[n], r));    \
                            float zd = __builtin_amdgcn_sqrtf(fmaxf(d2, 0.f));    \
                            float th = sel4(AJC[n], r) - zd;                      \
                            ll += __expf(th);  /* bit-identical -> exact cancel */\
                        }                                                         \
            }                                                                     \
        }                                                                         \
        __builtin_amdgcn_sched_barrier(0);                                        \
        if ((t) + 2 < NT) ALOAD(ACUR, (t) + 2);                                   \
    }

    for (int t = 0; t < NT; t += 2) {
        TBODY(t,     Aa, vj0, aj0, vj1, aj1);
        TBODY(t + 1, Ab, vj1, aj1, vj0, aj0);
    }

    // wave reduce then block reduce (fixed order -> deterministic)
    for (int off = 32; off; off >>= 1) ll += __shfl_xor(ll, off);
    if (lane == 0) red[wid] = ll;
    __syncthreads();
    if (tid == 0) partials[blk] = red[0] + red[1] + red[2] + red[3];
}

// ---------------- final deterministic reduction ----------------
__global__ __launch_bounds__(256) void final_kernel(const float* __restrict__ partials,
                                                    float* __restrict__ out) {
    int tid = threadIdx.x;
    float sum = 0.f;
    for (int idx = tid; idx < 512; idx += 256) sum += partials[idx];
    for (int off = 32; off; off >>= 1) sum += __shfl_xor(sum, off);
    __shared__ float red[4];
    if ((tid & 63) == 0) red[tid >> 6] = sum;
    __syncthreads();
    if (tid == 0) out[0] = 0.5f * (red[0] + red[1] + red[2] + red[3]);
}

extern "C" void kernel_launch(void* const* d_in, const int* in_sizes, int n_in,
                              void* d_out, int out_size, void* d_ws, size_t ws_size,
                              hipStream_t stream) {
    const int*   A     = (const int*)d_in[0];
    const float* alpha = (const float*)d_in[1];
    const float* Z     = (const float*)d_in[2];
    float* out = (float*)d_out;

    char* ws = (char*)d_ws;
    unsigned short* Zb = (unsigned short*)ws;                    // N*D*2 = 1 MB
    float* u        = (float*)(ws + (size_t)NN * DD * 2);        // 32 KB
    float* v        = u + NN;                                    // 32 KB
    float* partials = v + NN;                                    // 512 floats

    prep_kernel<<<NN / 4, 256, 0, stream>>>(Z, Zb, u, v);
    main_kernel<<<512, 256, 0, stream>>>(Zb, u, v, alpha, A, partials);
    final_kernel<<<1, 256, 0, stream>>>(partials, out);
}